// Round 8
// baseline (78.961 us; speedup 1.0000x reference)
//
#include <hip/hip_runtime.h>
#include <hip/hip_bf16.h>

// Problem dims (fixed by the reference)
#define O_FEAT 14336
#define I_FEAT 4096
#define BATCH  32
#define NSCALE (I_FEAT / 16)    // 256 scale blocks per output row
#define KSLICES 8
#define KPER (I_FEAT / KSLICES) // 512
#define NKT (I_FEAT / 32)       // 128 k-steps of 32

// GEOMETRY (R6 lesson): 256 threads/block = FOUR wave64s.
// Each wave covers 16 output columns (lane&15), waves 0..3 -> offsets [0,64).
// A block owns 64 distinct outputs; grid.x = O_FEAT/64 = 224 tiles exactly.

typedef __attribute__((ext_vector_type(8))) short bf16x8;
typedef __attribute__((ext_vector_type(4))) float f32x4;

// Round-to-nearest-even f32 -> bf16 (bit pattern), matches jnp astype(bfloat16)
__device__ __forceinline__ short f2bf(float f) {
    unsigned u = __float_as_uint(f);
    u += 0x7FFF + ((u >> 16) & 1);
    return (short)(u >> 16);
}

__device__ __forceinline__ float bf16_round_f32(float f) {
    unsigned u = __float_as_uint(f);
    u += 0x7FFF + ((u >> 16) & 1);
    u &= 0xFFFF0000u;
    return __uint_as_float(u);
}

// HW packed f32->bf16 RNE conversion: dst[15:0]=bf16(a), dst[31:16]=bf16(b).
__device__ __forceinline__ unsigned cvt_pk_bf16(float a, float b) {
    unsigned r;
    asm("v_cvt_pk_bf16_f32 %0, %1, %2" : "=v"(r) : "v"(a), "v"(b));
    return r;
}

// Nontemporal float4 load (q is streamed once; keep it out of the hot L2 set).
// NOTE: __builtin_nontemporal_load requires scalar/ext-vector types, not
// HIP_vector_type -- load as f32x4 (ext_vector) and convert.
__device__ __forceinline__ float4 ntload4(const float* p) {
    f32x4 v = __builtin_nontemporal_load((const f32x4*)p);
    float4 r; r.x = v[0]; r.y = v[1]; r.z = v[2]; r.w = v[3];
    return r;
}

// ---------------------------------------------------------------------------
// Prep: pack x into bf16 MFMA A-fragments; gemm loads each fragment as ONE
// lane-contiguous dwordx4 (L2-resident, 256 KB total).
// xf[kt][g][lane][8 bf16]: lane l holds batch row r=g*16+(l&15),
// kb = kt*32 + (l>>4)*4; elems 0-3 = x[r][kb..+3], 4-7 = x[r][kb+16..+19].
// ---------------------------------------------------------------------------
__global__ void w4a8_xpack_kernel(const float* __restrict__ x, unsigned* __restrict__ xf) {
    const int t = blockIdx.x * blockDim.x + threadIdx.x;
    if (t >= NKT * 2 * 64) return;
    const int lane = t & 63;
    const int g    = (t >> 6) & 1;
    const int kt   = t >> 7;
    const int r    = g * 16 + (lane & 15);
    const int kb   = kt * 32 + ((lane >> 4) << 2);
    const float* xr = x + (size_t)r * I_FEAT + kb;
    const float4 a = *(const float4*)xr;
    const float4 b = *(const float4*)(xr + 16);
    uint4 o;
    o.x = cvt_pk_bf16(a.x, a.y);
    o.y = cvt_pk_bf16(a.z, a.w);
    o.z = cvt_pk_bf16(b.x, b.y);
    o.w = cvt_pk_bf16(b.z, b.w);
    *(uint4*)(xf + (size_t)t * 4) = o;
}

// ---------------------------------------------------------------------------
// GEMM, 64-k-wide iterations with depth-2 register pipeline (9 loads/iter),
// peeled final iteration, cvt_pk dequant, nontemporal q loads.
// Each block: 64 distinct outputs x KPER k. grid = (224, KSLICES).
// ---------------------------------------------------------------------------
__global__ __launch_bounds__(256) void w4a8_gemm_pipe(
    const float* __restrict__ q,          // [14336][4096] fp32
    const float* __restrict__ sc,         // [14336][256] fp32
    const unsigned* __restrict__ xf,      // packed bf16 A-fragments
    float* __restrict__ part)             // [KSLICES][32][14336]
{
    const int lane = threadIdx.x & 63;
    const int wave = threadIdx.x >> 6;   // 0..3 (256 threads = 4 wave64s)
    const int o    = blockIdx.x * 64 + wave * 16 + (lane & 15);
    const int kq_off = (lane >> 4) * 4;
    const int k0   = blockIdx.y * KPER;
    const int kend = k0 + KPER;

    f32x4 acc_lo = {0.f, 0.f, 0.f, 0.f};
    f32x4 acc_hi = {0.f, 0.f, 0.f, 0.f};

    const float* qrow = q  + (size_t)o * I_FEAT;
    const float* srow = sc + (size_t)o * NSCALE;
    const unsigned* xfl = xf + (size_t)lane * 4; // + ((k>>5)*2+g)*256 (uints)

    // ---- prologue: load iteration k0 (2 MFMA k-steps = 64 k) ----
    float4 cq0 = ntload4(qrow + k0 + kq_off);
    float4 cq1 = ntload4(qrow + k0 + kq_off + 16);
    float4 cq2 = ntload4(qrow + k0 + kq_off + 32);
    float4 cq3 = ntload4(qrow + k0 + kq_off + 48);
    float4 csv = *(const float4*)(srow + (k0 >> 4));
    uint4  cf0 = *(const uint4*)(xfl + (size_t)((k0 >> 5) * 2 + 0) * 256);
    uint4  cf1 = *(const uint4*)(xfl + (size_t)((k0 >> 5) * 2 + 1) * 256);
    uint4  cf2 = *(const uint4*)(xfl + (size_t)((k0 >> 5) * 2 + 2) * 256);
    uint4  cf3 = *(const uint4*)(xfl + (size_t)((k0 >> 5) * 2 + 3) * 256);

#define COMPUTE_STEP()                                                          \
    {                                                                           \
        uint4 bu0, bu1;                                                         \
        bu0.x = cvt_pk_bf16(cq0.x * csv.x, cq0.y * csv.x);                      \
        bu0.y = cvt_pk_bf16(cq0.z * csv.x, cq0.w * csv.x);                      \
        bu0.z = cvt_pk_bf16(cq1.x * csv.y, cq1.y * csv.y);                      \
        bu0.w = cvt_pk_bf16(cq1.z * csv.y, cq1.w * csv.y);                      \
        bu1.x = cvt_pk_bf16(cq2.x * csv.z, cq2.y * csv.z);                      \
        bu1.y = cvt_pk_bf16(cq2.z * csv.z, cq2.w * csv.z);                      \
        bu1.z = cvt_pk_bf16(cq3.x * csv.w, cq3.y * csv.w);                      \
        bu1.w = cvt_pk_bf16(cq3.z * csv.w, cq3.w * csv.w);                      \
        acc_lo = __builtin_amdgcn_mfma_f32_16x16x32_bf16(*(const bf16x8*)&cf0, *(const bf16x8*)&bu0, acc_lo, 0, 0, 0); \
        acc_hi = __builtin_amdgcn_mfma_f32_16x16x32_bf16(*(const bf16x8*)&cf1, *(const bf16x8*)&bu0, acc_hi, 0, 0, 0); \
        acc_lo = __builtin_amdgcn_mfma_f32_16x16x32_bf16(*(const bf16x8*)&cf2, *(const bf16x8*)&bu1, acc_lo, 0, 0, 0); \
        acc_hi = __builtin_amdgcn_mfma_f32_16x16x32_bf16(*(const bf16x8*)&cf3, *(const bf16x8*)&bu1, acc_hi, 0, 0, 0); \
    }

    // ---- main loop: prefetch next 64-k group, compute current ----
    for (int kk = k0; kk + 64 < kend; kk += 64) {
        const int kn = kk + 64;
        const float4 nq0 = ntload4(qrow + kn + kq_off);
        const float4 nq1 = ntload4(qrow + kn + kq_off + 16);
        const float4 nq2 = ntload4(qrow + kn + kq_off + 32);
        const float4 nq3 = ntload4(qrow + kn + kq_off + 48);
        const float4 nsv = *(const float4*)(srow + (kn >> 4));
        const uint4  nf0 = *(const uint4*)(xfl + (size_t)((kn >> 5) * 2 + 0) * 256);
        const uint4  nf1 = *(const uint4*)(xfl + (size_t)((kn >> 5) * 2 + 1) * 256);
        const uint4  nf2 = *(const uint4*)(xfl + (size_t)((kn >> 5) * 2 + 2) * 256);
        const uint4  nf3 = *(const uint4*)(xfl + (size_t)((kn >> 5) * 2 + 3) * 256);

        COMPUTE_STEP();

        cq0 = nq0; cq1 = nq1; cq2 = nq2; cq3 = nq3; csv = nsv;
        cf0 = nf0; cf1 = nf1; cf2 = nf2; cf3 = nf3;
    }
    // ---- peeled last iteration: no prefetch ----
    COMPUTE_STEP();
#undef COMPUTE_STEP

    // C/D layout: col = lane&15 (-> o), row = (lane>>4)*4 + reg (-> batch)
    const int row = (lane >> 4) * 4;
    float* base = part + (size_t)blockIdx.y * ((size_t)BATCH * O_FEAT);
#pragma unroll
    for (int r = 0; r < 4; ++r) {
        base[(size_t)(row + r) * O_FEAT + o] = acc_lo[r];
        base[(size_t)(16 + row + r) * O_FEAT + o] = acc_hi[r];
    }
}

// ---------------------------------------------------------------------------
// Fallback (small ws): direct x loads, atomic epilogue. Same 64-col tiling.
// ---------------------------------------------------------------------------
__global__ __launch_bounds__(256) void w4a8_gemm_atomic(
    const float* __restrict__ x, const float* __restrict__ q,
    const float* __restrict__ sc, float* __restrict__ outp)
{
    const int lane = threadIdx.x & 63;
    const int wave = threadIdx.x >> 6;
    const int o    = blockIdx.x * 64 + wave * 16 + (lane & 15);
    const int kq_off = (lane >> 4) * 4;
    const int k0   = blockIdx.y * KPER;

    f32x4 acc_lo = {0.f, 0.f, 0.f, 0.f};
    f32x4 acc_hi = {0.f, 0.f, 0.f, 0.f};

    const float* qrow = q  + (size_t)o * I_FEAT;
    const float* srow = sc + (size_t)o * NSCALE;
    const float* xlo  = x  + (size_t)(lane & 15) * I_FEAT;
    const float* xhi  = xlo + (size_t)16 * I_FEAT;

#pragma unroll 4
    for (int kk = k0; kk < k0 + KPER; kk += 32) {
        const int kq = kk + kq_off;
        const float4 q0  = *(const float4*)(qrow + kq);
        const float4 q1  = *(const float4*)(qrow + kq + 16);
        const float2 s   = *(const float2*)(srow + (kk >> 4));
        const float4 xa0 = *(const float4*)(xlo + kq);
        const float4 xa1 = *(const float4*)(xlo + kq + 16);
        const float4 xb0 = *(const float4*)(xhi + kq);
        const float4 xb1 = *(const float4*)(xhi + kq + 16);

        bf16x8 bfrag, alo, ahi;
        bfrag[0] = f2bf(q0.x * s.x); bfrag[1] = f2bf(q0.y * s.x);
        bfrag[2] = f2bf(q0.z * s.x); bfrag[3] = f2bf(q0.w * s.x);
        bfrag[4] = f2bf(q1.x * s.y); bfrag[5] = f2bf(q1.y * s.y);
        bfrag[6] = f2bf(q1.z * s.y); bfrag[7] = f2bf(q1.w * s.y);
        alo[0] = f2bf(xa0.x); alo[1] = f2bf(xa0.y); alo[2] = f2bf(xa0.z); alo[3] = f2bf(xa0.w);
        alo[4] = f2bf(xa1.x); alo[5] = f2bf(xa1.y); alo[6] = f2bf(xa1.z); alo[7] = f2bf(xa1.w);
        ahi[0] = f2bf(xb0.x); ahi[1] = f2bf(xb0.y); ahi[2] = f2bf(xb0.z); ahi[3] = f2bf(xb0.w);
        ahi[4] = f2bf(xb1.x); ahi[5] = f2bf(xb1.y); ahi[6] = f2bf(xb1.z); ahi[7] = f2bf(xb1.w);

        acc_lo = __builtin_amdgcn_mfma_f32_16x16x32_bf16(alo, bfrag, acc_lo, 0, 0, 0);
        acc_hi = __builtin_amdgcn_mfma_f32_16x16x32_bf16(ahi, bfrag, acc_hi, 0, 0, 0);
    }

    const int row = (lane >> 4) * 4;
#pragma unroll
    for (int r = 0; r < 4; ++r) {
        atomicAdd(&outp[(size_t)(row + r) * O_FEAT + o], acc_lo[r]);
        atomicAdd(&outp[(size_t)(16 + row + r) * O_FEAT + o], acc_hi[r]);
    }
}

__global__ void w4a8_reduce_kernel(const float* __restrict__ part, float* __restrict__ out) {
    const int i = blockIdx.x * blockDim.x + threadIdx.x; // float4 index
    if (i >= (BATCH * O_FEAT) / 4) return;
    float4 s = {0.f, 0.f, 0.f, 0.f};
#pragma unroll
    for (int sl = 0; sl < KSLICES; ++sl) {
        const float4 p = *(const float4*)(part + (size_t)sl * BATCH * O_FEAT + (size_t)i * 4);
        s.x += p.x; s.y += p.y; s.z += p.z; s.w += p.w;
    }
    s.x = bf16_round_f32(s.x); s.y = bf16_round_f32(s.y);
    s.z = bf16_round_f32(s.z); s.w = bf16_round_f32(s.w);
    *(float4*)(out + (size_t)i * 4) = s;
}

extern "C" void kernel_launch(void* const* d_in, const int* in_sizes, int n_in,
                              void* d_out, int out_size, void* d_ws, size_t ws_size,
                              hipStream_t stream) {
    const float* x  = (const float*)d_in[0];  // [32,1,4096]
    const float* q  = (const float*)d_in[1];  // [14336,4096]
    const float* sc = (const float*)d_in[2];  // [14336,256]
    float* out = (float*)d_out;               // [32,1,14336] fp32

    const size_t partial_bytes = (size_t)KSLICES * BATCH * O_FEAT * sizeof(float);
    const size_t xf_off   = (partial_bytes + 255) & ~(size_t)255;
    const size_t xf_bytes = (size_t)NKT * 2 * 64 * 8 * sizeof(unsigned short);
    dim3 grid(O_FEAT / 64, KSLICES);   // (224, 8): 64 distinct outputs per block

    if (ws_size >= xf_off + xf_bytes) {
        float* part = (float*)d_ws;
        unsigned* xf = (unsigned*)((char*)d_ws + xf_off);
        w4a8_xpack_kernel<<<(NKT * 2 * 64 + 255) / 256, 256, 0, stream>>>(x, xf);
        w4a8_gemm_pipe<<<grid, 256, 0, stream>>>(q, sc, xf, part);
        const int n4 = (BATCH * O_FEAT) / 4; // 114688
        w4a8_reduce_kernel<<<(n4 + 255) / 256, 256, 0, stream>>>(part, out);
    } else {
        (void)hipMemsetAsync(d_out, 0, (size_t)BATCH * O_FEAT * sizeof(float), stream);
        w4a8_gemm_atomic<<<grid, 256, 0, stream>>>(x, q, sc, out);
    }
}

// Round 9
// 62.541 us; speedup vs baseline: 1.2626x; 1.2626x over previous
//
#include <hip/hip_runtime.h>
#include <hip/hip_bf16.h>

// Problem dims (fixed by the reference)
#define O_FEAT 14336
#define I_FEAT 4096
#define BATCH  32
#define NSCALE (I_FEAT / 16)    // 256 scale blocks per output row
#define KSLICES 4
#define KPER (I_FEAT / KSLICES) // 1024
#define NKT (I_FEAT / 32)       // 128 k-steps of 32

// GEOMETRY (R6 lesson): 256 threads/block = FOUR wave64s.
// Each wave covers 16 output columns (lane&15), waves 0..3 -> offsets [0,64).
// A block owns 64 distinct outputs; grid.x = O_FEAT/64 = 224 tiles exactly.

typedef __attribute__((ext_vector_type(8))) short bf16x8;
typedef __attribute__((ext_vector_type(4))) float f32x4;

// Round-to-nearest-even f32 -> bf16 (bit pattern), matches jnp astype(bfloat16)
__device__ __forceinline__ short f2bf(float f) {
    unsigned u = __float_as_uint(f);
    u += 0x7FFF + ((u >> 16) & 1);
    return (short)(u >> 16);
}

__device__ __forceinline__ float bf16_round_f32(float f) {
    unsigned u = __float_as_uint(f);
    u += 0x7FFF + ((u >> 16) & 1);
    u &= 0xFFFF0000u;
    return __uint_as_float(u);
}

// HW packed f32->bf16 RNE: dst[15:0]=bf16(a), dst[31:16]=bf16(b).
__device__ __forceinline__ unsigned cvt_pk_bf16(float a, float b) {
    unsigned r;
    asm("v_cvt_pk_bf16_f32 %0, %1, %2" : "=v"(r) : "v"(a), "v"(b));
    return r;
}

// ---------------------------------------------------------------------------
// Prep: pack x into bf16 MFMA A-fragments; gemm loads each fragment as ONE
// lane-contiguous dwordx4 (L2-resident, 256 KB total).
// xf[kt][g][lane][8 bf16]: lane l holds batch row r=g*16+(l&15),
// kb = kt*32 + (l>>4)*4; elems 0-3 = x[r][kb..+3], 4-7 = x[r][kb+16..+19].
// ---------------------------------------------------------------------------
__global__ void w4a8_xpack_kernel(const float* __restrict__ x, unsigned* __restrict__ xf) {
    const int t = blockIdx.x * blockDim.x + threadIdx.x;
    if (t >= NKT * 2 * 64) return;
    const int lane = t & 63;
    const int g    = (t >> 6) & 1;
    const int kt   = t >> 7;
    const int r    = g * 16 + (lane & 15);
    const int kb   = kt * 32 + ((lane >> 4) << 2);
    const float* xr = x + (size_t)r * I_FEAT + kb;
    const float4 a = *(const float4*)xr;
    const float4 b = *(const float4*)(xr + 16);
    uint4 o;
    o.x = cvt_pk_bf16(a.x, a.y);
    o.y = cvt_pk_bf16(a.z, a.w);
    o.z = cvt_pk_bf16(b.x, b.y);
    o.w = cvt_pk_bf16(b.z, b.w);
    *(uint4*)(xf + (size_t)t * 4) = o;
}

// ---------------------------------------------------------------------------
// GEMM, 64-k-wide iterations, depth-2 register pipeline (9 loads/iter),
// peeled final iteration, cvt_pk dequant, PLAIN q loads (nt regressed, R8).
// Partials stored as bf16 in transposed layout part[sl][o][b] -- two 8B
// packed stores per lane, wave-contiguous 1KB. grid = (224, KSLICES).
// ---------------------------------------------------------------------------
__global__ __launch_bounds__(256) void w4a8_gemm_pipe(
    const float* __restrict__ q,          // [14336][4096] fp32
    const float* __restrict__ sc,         // [14336][256] fp32
    const unsigned* __restrict__ xf,      // packed bf16 A-fragments
    unsigned short* __restrict__ part)    // [KSLICES][O_FEAT][BATCH] bf16
{
    const int lane = threadIdx.x & 63;
    const int wave = threadIdx.x >> 6;   // 0..3 (256 threads = 4 wave64s)
    const int o    = blockIdx.x * 64 + wave * 16 + (lane & 15);
    const int kq_off = (lane >> 4) * 4;
    const int k0   = blockIdx.y * KPER;
    const int kend = k0 + KPER;

    f32x4 acc_lo = {0.f, 0.f, 0.f, 0.f};
    f32x4 acc_hi = {0.f, 0.f, 0.f, 0.f};

    const float* qrow = q  + (size_t)o * I_FEAT;
    const float* srow = sc + (size_t)o * NSCALE;
    const unsigned* xfl = xf + (size_t)lane * 4; // + ((k>>5)*2+g)*256 (uints)

    // ---- prologue: load iteration k0 (2 MFMA k-steps = 64 k) ----
    float4 cq0 = *(const float4*)(qrow + k0 + kq_off);
    float4 cq1 = *(const float4*)(qrow + k0 + kq_off + 16);
    float4 cq2 = *(const float4*)(qrow + k0 + kq_off + 32);
    float4 cq3 = *(const float4*)(qrow + k0 + kq_off + 48);
    float4 csv = *(const float4*)(srow + (k0 >> 4));
    uint4  cf0 = *(const uint4*)(xfl + (size_t)((k0 >> 5) * 2 + 0) * 256);
    uint4  cf1 = *(const uint4*)(xfl + (size_t)((k0 >> 5) * 2 + 1) * 256);
    uint4  cf2 = *(const uint4*)(xfl + (size_t)((k0 >> 5) * 2 + 2) * 256);
    uint4  cf3 = *(const uint4*)(xfl + (size_t)((k0 >> 5) * 2 + 3) * 256);

#define COMPUTE_STEP()                                                          \
    {                                                                           \
        uint4 bu0, bu1;                                                         \
        bu0.x = cvt_pk_bf16(cq0.x * csv.x, cq0.y * csv.x);                      \
        bu0.y = cvt_pk_bf16(cq0.z * csv.x, cq0.w * csv.x);                      \
        bu0.z = cvt_pk_bf16(cq1.x * csv.y, cq1.y * csv.y);                      \
        bu0.w = cvt_pk_bf16(cq1.z * csv.y, cq1.w * csv.y);                      \
        bu1.x = cvt_pk_bf16(cq2.x * csv.z, cq2.y * csv.z);                      \
        bu1.y = cvt_pk_bf16(cq2.z * csv.z, cq2.w * csv.z);                      \
        bu1.z = cvt_pk_bf16(cq3.x * csv.w, cq3.y * csv.w);                      \
        bu1.w = cvt_pk_bf16(cq3.z * csv.w, cq3.w * csv.w);                      \
        acc_lo = __builtin_amdgcn_mfma_f32_16x16x32_bf16(*(const bf16x8*)&cf0, *(const bf16x8*)&bu0, acc_lo, 0, 0, 0); \
        acc_hi = __builtin_amdgcn_mfma_f32_16x16x32_bf16(*(const bf16x8*)&cf1, *(const bf16x8*)&bu0, acc_hi, 0, 0, 0); \
        acc_lo = __builtin_amdgcn_mfma_f32_16x16x32_bf16(*(const bf16x8*)&cf2, *(const bf16x8*)&bu1, acc_lo, 0, 0, 0); \
        acc_hi = __builtin_amdgcn_mfma_f32_16x16x32_bf16(*(const bf16x8*)&cf3, *(const bf16x8*)&bu1, acc_hi, 0, 0, 0); \
    }

    // ---- main loop: prefetch next 64-k group, compute current ----
    for (int kk = k0; kk + 64 < kend; kk += 64) {
        const int kn = kk + 64;
        const float4 nq0 = *(const float4*)(qrow + kn + kq_off);
        const float4 nq1 = *(const float4*)(qrow + kn + kq_off + 16);
        const float4 nq2 = *(const float4*)(qrow + kn + kq_off + 32);
        const float4 nq3 = *(const float4*)(qrow + kn + kq_off + 48);
        const float4 nsv = *(const float4*)(srow + (kn >> 4));
        const uint4  nf0 = *(const uint4*)(xfl + (size_t)((kn >> 5) * 2 + 0) * 256);
        const uint4  nf1 = *(const uint4*)(xfl + (size_t)((kn >> 5) * 2 + 1) * 256);
        const uint4  nf2 = *(const uint4*)(xfl + (size_t)((kn >> 5) * 2 + 2) * 256);
        const uint4  nf3 = *(const uint4*)(xfl + (size_t)((kn >> 5) * 2 + 3) * 256);

        COMPUTE_STEP();

        cq0 = nq0; cq1 = nq1; cq2 = nq2; cq3 = nq3; csv = nsv;
        cf0 = nf0; cf1 = nf1; cf2 = nf2; cf3 = nf3;
    }
    // ---- peeled last iteration: no prefetch ----
    COMPUTE_STEP();
#undef COMPUTE_STEP

    // ---- epilogue: bf16 partials, transposed layout part[sl][o][b] ----
    // acc reg r -> batch row = (lane>>4)*4 + r (lo) / +16 (hi), column = o.
    const int row = (lane >> 4) * 4;
    unsigned short* pb = part + ((size_t)blockIdx.y * O_FEAT + o) * BATCH;
    uint2 plo, phi;
    plo.x = cvt_pk_bf16(acc_lo[0], acc_lo[1]);
    plo.y = cvt_pk_bf16(acc_lo[2], acc_lo[3]);
    phi.x = cvt_pk_bf16(acc_hi[0], acc_hi[1]);
    phi.y = cvt_pk_bf16(acc_hi[2], acc_hi[3]);
    *(uint2*)(pb + row)      = plo;   // rows row..row+3
    *(uint2*)(pb + 16 + row) = phi;   // rows 16+row..19+row
}

// ---------------------------------------------------------------------------
// Reduce: one thread per output column o; sum KSLICES bf16 partials in f32,
// round to bf16 precision, store fp32 out[b][o] (coalesced across threads).
// ---------------------------------------------------------------------------
__global__ void w4a8_reduce_kernel(const unsigned short* __restrict__ part,
                                   float* __restrict__ out) {
    const int o = blockIdx.x * blockDim.x + threadIdx.x;
    if (o >= O_FEAT) return;
    float s[BATCH];
#pragma unroll
    for (int b = 0; b < BATCH; ++b) s[b] = 0.f;
#pragma unroll
    for (int sl = 0; sl < KSLICES; ++sl) {
        const uint4* p = (const uint4*)(part + ((size_t)sl * O_FEAT + o) * BATCH);
#pragma unroll
        for (int j = 0; j < 4; ++j) {       // 8 bf16 per uint4
            const uint4 v = p[j];
            s[j*8+0] += __uint_as_float(v.x << 16);
            s[j*8+1] += __uint_as_float(v.x & 0xFFFF0000u);
            s[j*8+2] += __uint_as_float(v.y << 16);
            s[j*8+3] += __uint_as_float(v.y & 0xFFFF0000u);
            s[j*8+4] += __uint_as_float(v.z << 16);
            s[j*8+5] += __uint_as_float(v.z & 0xFFFF0000u);
            s[j*8+6] += __uint_as_float(v.w << 16);
            s[j*8+7] += __uint_as_float(v.w & 0xFFFF0000u);
        }
    }
#pragma unroll
    for (int b = 0; b < BATCH; ++b)
        out[(size_t)b * O_FEAT + o] = bf16_round_f32(s[b]);
}

// ---------------------------------------------------------------------------
// Fallback (small ws): direct x loads, atomic epilogue. Same 64-col tiling.
// ---------------------------------------------------------------------------
__global__ __launch_bounds__(256) void w4a8_gemm_atomic(
    const float* __restrict__ x, const float* __restrict__ q,
    const float* __restrict__ sc, float* __restrict__ outp)
{
    const int lane = threadIdx.x & 63;
    const int wave = threadIdx.x >> 6;
    const int o    = blockIdx.x * 64 + wave * 16 + (lane & 15);
    const int kq_off = (lane >> 4) * 4;
    const int k0   = blockIdx.y * KPER;

    f32x4 acc_lo = {0.f, 0.f, 0.f, 0.f};
    f32x4 acc_hi = {0.f, 0.f, 0.f, 0.f};

    const float* qrow = q  + (size_t)o * I_FEAT;
    const float* srow = sc + (size_t)o * NSCALE;
    const float* xlo  = x  + (size_t)(lane & 15) * I_FEAT;
    const float* xhi  = xlo + (size_t)16 * I_FEAT;

#pragma unroll 4
    for (int kk = k0; kk < k0 + KPER; kk += 32) {
        const int kq = kk + kq_off;
        const float4 q0  = *(const float4*)(qrow + kq);
        const float4 q1  = *(const float4*)(qrow + kq + 16);
        const float2 s   = *(const float2*)(srow + (kk >> 4));
        const float4 xa0 = *(const float4*)(xlo + kq);
        const float4 xa1 = *(const float4*)(xlo + kq + 16);
        const float4 xb0 = *(const float4*)(xhi + kq);
        const float4 xb1 = *(const float4*)(xhi + kq + 16);

        bf16x8 bfrag, alo, ahi;
        bfrag[0] = f2bf(q0.x * s.x); bfrag[1] = f2bf(q0.y * s.x);
        bfrag[2] = f2bf(q0.z * s.x); bfrag[3] = f2bf(q0.w * s.x);
        bfrag[4] = f2bf(q1.x * s.y); bfrag[5] = f2bf(q1.y * s.y);
        bfrag[6] = f2bf(q1.z * s.y); bfrag[7] = f2bf(q1.w * s.y);
        alo[0] = f2bf(xa0.x); alo[1] = f2bf(xa0.y); alo[2] = f2bf(xa0.z); alo[3] = f2bf(xa0.w);
        alo[4] = f2bf(xa1.x); alo[5] = f2bf(xa1.y); alo[6] = f2bf(xa1.z); alo[7] = f2bf(xa1.w);
        ahi[0] = f2bf(xb0.x); ahi[1] = f2bf(xb0.y); ahi[2] = f2bf(xb0.z); ahi[3] = f2bf(xb0.w);
        ahi[4] = f2bf(xb1.x); ahi[5] = f2bf(xb1.y); ahi[6] = f2bf(xb1.z); ahi[7] = f2bf(xb1.w);

        acc_lo = __builtin_amdgcn_mfma_f32_16x16x32_bf16(alo, bfrag, acc_lo, 0, 0, 0);
        acc_hi = __builtin_amdgcn_mfma_f32_16x16x32_bf16(ahi, bfrag, acc_hi, 0, 0, 0);
    }

    const int row = (lane >> 4) * 4;
#pragma unroll
    for (int r = 0; r < 4; ++r) {
        atomicAdd(&outp[(size_t)(row + r) * O_FEAT + o], acc_lo[r]);
        atomicAdd(&outp[(size_t)(16 + row + r) * O_FEAT + o], acc_hi[r]);
    }
}

extern "C" void kernel_launch(void* const* d_in, const int* in_sizes, int n_in,
                              void* d_out, int out_size, void* d_ws, size_t ws_size,
                              hipStream_t stream) {
    const float* x  = (const float*)d_in[0];  // [32,1,4096]
    const float* q  = (const float*)d_in[1];  // [14336,4096]
    const float* sc = (const float*)d_in[2];  // [14336,256]
    float* out = (float*)d_out;               // [32,1,14336] fp32

    const size_t partial_bytes = (size_t)KSLICES * O_FEAT * BATCH * sizeof(unsigned short);
    const size_t xf_off   = (partial_bytes + 255) & ~(size_t)255;
    const size_t xf_bytes = (size_t)NKT * 2 * 64 * 8 * sizeof(unsigned short);
    dim3 grid(O_FEAT / 64, KSLICES);   // (224, 4): 64 distinct outputs per block

    if (ws_size >= xf_off + xf_bytes) {
        unsigned short* part = (unsigned short*)d_ws;
        unsigned* xf = (unsigned*)((char*)d_ws + xf_off);
        w4a8_xpack_kernel<<<(NKT * 2 * 64 + 255) / 256, 256, 0, stream>>>(x, xf);
        w4a8_gemm_pipe<<<grid, 256, 0, stream>>>(q, sc, xf, part);
        w4a8_reduce_kernel<<<(O_FEAT + 255) / 256, 256, 0, stream>>>(part, out);
    } else {
        (void)hipMemsetAsync(d_out, 0, (size_t)BATCH * O_FEAT * sizeof(float), stream);
        w4a8_gemm_atomic<<<grid, 256, 0, stream>>>(x, q, sc, out);
    }
}

// Round 10
// 56.308 us; speedup vs baseline: 1.4023x; 1.1107x over previous
//
#include <hip/hip_runtime.h>
#include <hip/hip_bf16.h>

// Problem dims (fixed by the reference)
#define O_FEAT 14336
#define I_FEAT 4096
#define BATCH  32
#define NSCALE (I_FEAT / 16)    // 256 scale blocks per output row
#define KSLICES 8
#define KPER (I_FEAT / KSLICES) // 512
#define NKT (I_FEAT / 32)       // 128 k-steps of 32

// GEOMETRY (R6 lesson): 256 threads/block = FOUR wave64s.
// Each wave covers 16 output columns (lane&15), waves 0..3 -> offsets [0,64).
// A block owns 64 distinct outputs; grid.x = O_FEAT/64 = 224 tiles exactly.
// KSLICES=8 -> 1792 blocks = 7/CU (~28 waves/CU): R9 showed 3.5/CU starves
// latency hiding; keep 8 slices.

typedef __attribute__((ext_vector_type(8))) short bf16x8;
typedef __attribute__((ext_vector_type(4))) float f32x4;

// Round-to-nearest-even f32 -> bf16 (bit pattern), matches jnp astype(bfloat16)
__device__ __forceinline__ short f2bf(float f) {
    unsigned u = __float_as_uint(f);
    u += 0x7FFF + ((u >> 16) & 1);
    return (short)(u >> 16);
}

__device__ __forceinline__ float bf16_round_f32(float f) {
    unsigned u = __float_as_uint(f);
    u += 0x7FFF + ((u >> 16) & 1);
    u &= 0xFFFF0000u;
    return __uint_as_float(u);
}

// HW packed f32->bf16 RNE: dst[15:0]=bf16(a), dst[31:16]=bf16(b).
__device__ __forceinline__ unsigned cvt_pk_bf16(float a, float b) {
    unsigned r;
    asm("v_cvt_pk_bf16_f32 %0, %1, %2" : "=v"(r) : "v"(a), "v"(b));
    return r;
}

// ---------------------------------------------------------------------------
// Prep: pack x into bf16 MFMA A-fragments; gemm loads each fragment as ONE
// lane-contiguous dwordx4 (L2-resident, 256 KB total).
// xf[kt][g][lane][8 bf16]: lane l holds batch row r=g*16+(l&15),
// kb = kt*32 + (l>>4)*4; elems 0-3 = x[r][kb..+3], 4-7 = x[r][kb+16..+19].
// ---------------------------------------------------------------------------
__global__ void w4a8_xpack_kernel(const float* __restrict__ x, unsigned* __restrict__ xf) {
    const int t = blockIdx.x * blockDim.x + threadIdx.x;
    if (t >= NKT * 2 * 64) return;
    const int lane = t & 63;
    const int g    = (t >> 6) & 1;
    const int kt   = t >> 7;
    const int r    = g * 16 + (lane & 15);
    const int kb   = kt * 32 + ((lane >> 4) << 2);
    const float* xr = x + (size_t)r * I_FEAT + kb;
    const float4 a = *(const float4*)xr;
    const float4 b = *(const float4*)(xr + 16);
    uint4 o;
    o.x = cvt_pk_bf16(a.x, a.y);
    o.y = cvt_pk_bf16(a.z, a.w);
    o.z = cvt_pk_bf16(b.x, b.y);
    o.w = cvt_pk_bf16(b.z, b.w);
    *(uint4*)(xf + (size_t)t * 4) = o;
}

// ---------------------------------------------------------------------------
// GEMM, 64-k-wide iterations, depth-2 register pipeline (9 loads/iter),
// peeled final iteration, cvt_pk dequant, plain q loads (nt regressed, R8).
// Partials stored as bf16 in transposed layout part[sl][o][b] -- two 8B
// packed stores per lane, wave covers a contiguous 1KB. grid = (224, 8).
// ---------------------------------------------------------------------------
__global__ __launch_bounds__(256) void w4a8_gemm_pipe(
    const float* __restrict__ q,          // [14336][4096] fp32
    const float* __restrict__ sc,         // [14336][256] fp32
    const unsigned* __restrict__ xf,      // packed bf16 A-fragments
    unsigned short* __restrict__ part)    // [KSLICES][O_FEAT][BATCH] bf16
{
    const int lane = threadIdx.x & 63;
    const int wave = threadIdx.x >> 6;   // 0..3 (256 threads = 4 wave64s)
    const int o    = blockIdx.x * 64 + wave * 16 + (lane & 15);
    const int kq_off = (lane >> 4) * 4;
    const int k0   = blockIdx.y * KPER;
    const int kend = k0 + KPER;

    f32x4 acc_lo = {0.f, 0.f, 0.f, 0.f};
    f32x4 acc_hi = {0.f, 0.f, 0.f, 0.f};

    const float* qrow = q  + (size_t)o * I_FEAT;
    const float* srow = sc + (size_t)o * NSCALE;
    const unsigned* xfl = xf + (size_t)lane * 4; // + ((k>>5)*2+g)*256 (uints)

    // ---- prologue: load iteration k0 (2 MFMA k-steps = 64 k) ----
    float4 cq0 = *(const float4*)(qrow + k0 + kq_off);
    float4 cq1 = *(const float4*)(qrow + k0 + kq_off + 16);
    float4 cq2 = *(const float4*)(qrow + k0 + kq_off + 32);
    float4 cq3 = *(const float4*)(qrow + k0 + kq_off + 48);
    float4 csv = *(const float4*)(srow + (k0 >> 4));
    uint4  cf0 = *(const uint4*)(xfl + (size_t)((k0 >> 5) * 2 + 0) * 256);
    uint4  cf1 = *(const uint4*)(xfl + (size_t)((k0 >> 5) * 2 + 1) * 256);
    uint4  cf2 = *(const uint4*)(xfl + (size_t)((k0 >> 5) * 2 + 2) * 256);
    uint4  cf3 = *(const uint4*)(xfl + (size_t)((k0 >> 5) * 2 + 3) * 256);

#define COMPUTE_STEP()                                                          \
    {                                                                           \
        uint4 bu0, bu1;                                                         \
        bu0.x = cvt_pk_bf16(cq0.x * csv.x, cq0.y * csv.x);                      \
        bu0.y = cvt_pk_bf16(cq0.z * csv.x, cq0.w * csv.x);                      \
        bu0.z = cvt_pk_bf16(cq1.x * csv.y, cq1.y * csv.y);                      \
        bu0.w = cvt_pk_bf16(cq1.z * csv.y, cq1.w * csv.y);                      \
        bu1.x = cvt_pk_bf16(cq2.x * csv.z, cq2.y * csv.z);                      \
        bu1.y = cvt_pk_bf16(cq2.z * csv.z, cq2.w * csv.z);                      \
        bu1.z = cvt_pk_bf16(cq3.x * csv.w, cq3.y * csv.w);                      \
        bu1.w = cvt_pk_bf16(cq3.z * csv.w, cq3.w * csv.w);                      \
        acc_lo = __builtin_amdgcn_mfma_f32_16x16x32_bf16(*(const bf16x8*)&cf0, *(const bf16x8*)&bu0, acc_lo, 0, 0, 0); \
        acc_hi = __builtin_amdgcn_mfma_f32_16x16x32_bf16(*(const bf16x8*)&cf1, *(const bf16x8*)&bu0, acc_hi, 0, 0, 0); \
        acc_lo = __builtin_amdgcn_mfma_f32_16x16x32_bf16(*(const bf16x8*)&cf2, *(const bf16x8*)&bu1, acc_lo, 0, 0, 0); \
        acc_hi = __builtin_amdgcn_mfma_f32_16x16x32_bf16(*(const bf16x8*)&cf3, *(const bf16x8*)&bu1, acc_hi, 0, 0, 0); \
    }

    // ---- main loop: prefetch next 64-k group, compute current ----
    for (int kk = k0; kk + 64 < kend; kk += 64) {
        const int kn = kk + 64;
        const float4 nq0 = *(const float4*)(qrow + kn + kq_off);
        const float4 nq1 = *(const float4*)(qrow + kn + kq_off + 16);
        const float4 nq2 = *(const float4*)(qrow + kn + kq_off + 32);
        const float4 nq3 = *(const float4*)(qrow + kn + kq_off + 48);
        const float4 nsv = *(const float4*)(srow + (kn >> 4));
        const uint4  nf0 = *(const uint4*)(xfl + (size_t)((kn >> 5) * 2 + 0) * 256);
        const uint4  nf1 = *(const uint4*)(xfl + (size_t)((kn >> 5) * 2 + 1) * 256);
        const uint4  nf2 = *(const uint4*)(xfl + (size_t)((kn >> 5) * 2 + 2) * 256);
        const uint4  nf3 = *(const uint4*)(xfl + (size_t)((kn >> 5) * 2 + 3) * 256);

        COMPUTE_STEP();

        cq0 = nq0; cq1 = nq1; cq2 = nq2; cq3 = nq3; csv = nsv;
        cf0 = nf0; cf1 = nf1; cf2 = nf2; cf3 = nf3;
    }
    // ---- peeled last iteration: no prefetch ----
    COMPUTE_STEP();
#undef COMPUTE_STEP

    // ---- epilogue: bf16 partials, transposed layout part[sl][o][b] ----
    // acc reg r -> batch row = (lane>>4)*4 + r (lo) / +16 (hi), column = o.
    const int row = (lane >> 4) * 4;
    unsigned short* pb = part + ((size_t)blockIdx.y * O_FEAT + o) * BATCH;
    uint2 plo, phi;
    plo.x = cvt_pk_bf16(acc_lo[0], acc_lo[1]);
    plo.y = cvt_pk_bf16(acc_lo[2], acc_lo[3]);
    phi.x = cvt_pk_bf16(acc_hi[0], acc_hi[1]);
    phi.y = cvt_pk_bf16(acc_hi[2], acc_hi[3]);
    *(uint2*)(pb + row)      = plo;   // rows row..row+3
    *(uint2*)(pb + 16 + row) = phi;   // rows 16+row..19+row
}

// ---------------------------------------------------------------------------
// Reduce: one thread per output column o; sum KSLICES bf16 partials in f32,
// round to bf16 precision, store fp32 out[b][o] (coalesced across threads).
// ---------------------------------------------------------------------------
__global__ void w4a8_reduce_kernel(const unsigned short* __restrict__ part,
                                   float* __restrict__ out) {
    const int o = blockIdx.x * blockDim.x + threadIdx.x;
    if (o >= O_FEAT) return;
    float s[BATCH];
#pragma unroll
    for (int b = 0; b < BATCH; ++b) s[b] = 0.f;
#pragma unroll
    for (int sl = 0; sl < KSLICES; ++sl) {
        const uint4* p = (const uint4*)(part + ((size_t)sl * O_FEAT + o) * BATCH);
#pragma unroll
        for (int j = 0; j < 4; ++j) {       // 8 bf16 per uint4
            const uint4 v = p[j];
            s[j*8+0] += __uint_as_float(v.x << 16);
            s[j*8+1] += __uint_as_float(v.x & 0xFFFF0000u);
            s[j*8+2] += __uint_as_float(v.y << 16);
            s[j*8+3] += __uint_as_float(v.y & 0xFFFF0000u);
            s[j*8+4] += __uint_as_float(v.z << 16);
            s[j*8+5] += __uint_as_float(v.z & 0xFFFF0000u);
            s[j*8+6] += __uint_as_float(v.w << 16);
            s[j*8+7] += __uint_as_float(v.w & 0xFFFF0000u);
        }
    }
#pragma unroll
    for (int b = 0; b < BATCH; ++b)
        out[(size_t)b * O_FEAT + o] = bf16_round_f32(s[b]);
}

// ---------------------------------------------------------------------------
// Fallback (small ws): direct x loads, atomic epilogue. Same 64-col tiling.
// ---------------------------------------------------------------------------
__global__ __launch_bounds__(256) void w4a8_gemm_atomic(
    const float* __restrict__ x, const float* __restrict__ q,
    const float* __restrict__ sc, float* __restrict__ outp)
{
    const int lane = threadIdx.x & 63;
    const int wave = threadIdx.x >> 6;
    const int o    = blockIdx.x * 64 + wave * 16 + (lane & 15);
    const int kq_off = (lane >> 4) * 4;
    const int k0   = blockIdx.y * KPER;

    f32x4 acc_lo = {0.f, 0.f, 0.f, 0.f};
    f32x4 acc_hi = {0.f, 0.f, 0.f, 0.f};

    const float* qrow = q  + (size_t)o * I_FEAT;
    const float* srow = sc + (size_t)o * NSCALE;
    const float* xlo  = x  + (size_t)(lane & 15) * I_FEAT;
    const float* xhi  = xlo + (size_t)16 * I_FEAT;

#pragma unroll 4
    for (int kk = k0; kk < k0 + KPER; kk += 32) {
        const int kq = kk + kq_off;
        const float4 q0  = *(const float4*)(qrow + kq);
        const float4 q1  = *(const float4*)(qrow + kq + 16);
        const float2 s   = *(const float2*)(srow + (kk >> 4));
        const float4 xa0 = *(const float4*)(xlo + kq);
        const float4 xa1 = *(const float4*)(xlo + kq + 16);
        const float4 xb0 = *(const float4*)(xhi + kq);
        const float4 xb1 = *(const float4*)(xhi + kq + 16);

        bf16x8 bfrag, alo, ahi;
        bfrag[0] = f2bf(q0.x * s.x); bfrag[1] = f2bf(q0.y * s.x);
        bfrag[2] = f2bf(q0.z * s.x); bfrag[3] = f2bf(q0.w * s.x);
        bfrag[4] = f2bf(q1.x * s.y); bfrag[5] = f2bf(q1.y * s.y);
        bfrag[6] = f2bf(q1.z * s.y); bfrag[7] = f2bf(q1.w * s.y);
        alo[0] = f2bf(xa0.x); alo[1] = f2bf(xa0.y); alo[2] = f2bf(xa0.z); alo[3] = f2bf(xa0.w);
        alo[4] = f2bf(xa1.x); alo[5] = f2bf(xa1.y); alo[6] = f2bf(xa1.z); alo[7] = f2bf(xa1.w);
        ahi[0] = f2bf(xb0.x); ahi[1] = f2bf(xb0.y); ahi[2] = f2bf(xb0.z); ahi[3] = f2bf(xb0.w);
        ahi[4] = f2bf(xb1.x); ahi[5] = f2bf(xb1.y); ahi[6] = f2bf(xb1.z); ahi[7] = f2bf(xb1.w);

        acc_lo = __builtin_amdgcn_mfma_f32_16x16x32_bf16(alo, bfrag, acc_lo, 0, 0, 0);
        acc_hi = __builtin_amdgcn_mfma_f32_16x16x32_bf16(ahi, bfrag, acc_hi, 0, 0, 0);
    }

    const int row = (lane >> 4) * 4;
#pragma unroll
    for (int r = 0; r < 4; ++r) {
        atomicAdd(&outp[(size_t)(row + r) * O_FEAT + o], acc_lo[r]);
        atomicAdd(&outp[(size_t)(16 + row + r) * O_FEAT + o], acc_hi[r]);
    }
}

extern "C" void kernel_launch(void* const* d_in, const int* in_sizes, int n_in,
                              void* d_out, int out_size, void* d_ws, size_t ws_size,
                              hipStream_t stream) {
    const float* x  = (const float*)d_in[0];  // [32,1,4096]
    const float* q  = (const float*)d_in[1];  // [14336,4096]
    const float* sc = (const float*)d_in[2];  // [14336,256]
    float* out = (float*)d_out;               // [32,1,14336] fp32

    const size_t partial_bytes = (size_t)KSLICES * O_FEAT * BATCH * sizeof(unsigned short);
    const size_t xf_off   = (partial_bytes + 255) & ~(size_t)255;
    const size_t xf_bytes = (size_t)NKT * 2 * 64 * 8 * sizeof(unsigned short);
    dim3 grid(O_FEAT / 64, KSLICES);   // (224, 8): 64 distinct outputs per block, 7 blocks/CU

    if (ws_size >= xf_off + xf_bytes) {
        unsigned short* part = (unsigned short*)d_ws;
        unsigned* xf = (unsigned*)((char*)d_ws + xf_off);
        w4a8_xpack_kernel<<<(NKT * 2 * 64 + 255) / 256, 256, 0, stream>>>(x, xf);
        w4a8_gemm_pipe<<<grid, 256, 0, stream>>>(q, sc, xf, part);
        w4a8_reduce_kernel<<<(O_FEAT + 255) / 256, 256, 0, stream>>>(part, out);
    } else {
        (void)hipMemsetAsync(d_out, 0, (size_t)BATCH * O_FEAT * sizeof(float), stream);
        w4a8_gemm_atomic<<<grid, 256, 0, stream>>>(x, q, sc, out);
    }
}